// Round 2
// baseline (522.452 us; speedup 1.0000x reference)
//
#include <hip/hip_runtime.h>
#include <hip/hip_fp16.h>

#define HID 50
#define LAT 16
#define NW  4          // waves per block (independent after one-time dt staging)
#define BLK (NW * 64)
#define MPW 16         // batch elements per wave (one MFMA M-tile)

typedef __attribute__((ext_vector_type(8))) _Float16 half8v;  // 8 f16 = 4 VGPRs
typedef __attribute__((ext_vector_type(4))) float f32x4;
typedef __attribute__((ext_vector_type(2))) float f32x2;      // v_pk_*_f32 pair
typedef __attribute__((ext_vector_type(4))) unsigned uint4v;

#define MFMAH(a, b, c) __builtin_amdgcn_mfma_f32_16x16x32_f16(a, b, c, 0, 0, 0)

// pack two fp32 -> dword of 2 f16 (v_cvt_pkrtz_f16_f32, 1 instr)
__device__ __forceinline__ unsigned pkhf(float lo, float hi) {
    __half2 h = __float22half2_rn(float2{lo, hi});
    unsigned r;
    __builtin_memcpy(&r, &h, 4);
    return r;
}

// kappa-label -> hidden-unit map (R15 repack).  Tiles 0-2 hold real units
// 0..47; tile 3 holds units 48,49 at m=0,1 (q=0), the bias/sat slot at
// kappa==38 (m=2, q=0), everything else dead.  odef/decode evaluate the
// activation on 14 lane-values; the sat slot is the constant biasdw dword.
__device__ __forceinline__ int unitmap(int k, bool& dead, bool& sat) {
    dead = false; sat = false;
    int u = k;
    if (k == 36)                          u = 48;
    else if (k == 37)                     u = 49;
    else if (k == 38)                     sat = true;
    else if (k == 39)                     dead = true;
    else if (k >= 44 && k < 48)           dead = true;
    else if ((k >= 48 && k < 52) || (k >= 56 && k < 60)) u = k - 12;
    else if (k >= 52 && k < 56)           dead = true;
    else if (k >= 60)                     dead = true;
    return u;   // k<36 (not 36-39) and 40-43: identity
}

// ---- A-frag builders (weights as f16 MFMA A-operand; one-time setup) ----
// Layer-1: A-row m of tile ti holds unit unitmap(kappa(ti,m)),
// kappa(ti,m)=32*(ti>>1)+8*(m>>2)+4*(ti&1)+(m&3) -- CD regs land exactly on
// GEMM2 B-frag slots.  k-slot (q,j): j<4 -> input row 4q+j; (q==0,j==4) ->
// bias*scale.  sat/dead columns all-zero (bias enters via GEMM2 B const).
__device__ __forceinline__ half8v afrag1(const float* __restrict__ W, const float* __restrict__ bias,
                                         int Kreal, int ti, int q, int m, float scale) {
    int kap = 32 * (ti >> 1) + 8 * (m >> 2) + 4 * (ti & 1) + (m & 3);
    bool dead, sat;
    int u = unitmap(kap, dead, sat);
    float e[8];
#pragma unroll
    for (int j = 0; j < 8; j++) {
        float f = 0.0f;
        if (!dead && !sat) {
            if (j < 4) {
                int row = 4 * q + j;
                if (row < Kreal) f = W[row * HID + u] * scale;
            } else if (j == 4 && q == 0) f = bias[u] * scale;
        }
        e[j] = f;
    }
    uint4v d;
#pragma unroll
    for (int p = 0; p < 4; p++) d[p] = pkhf(e[2 * p], e[2 * p + 1]);
    return __builtin_bit_cast(half8v, d);
}

// Layer-2: A2[m][kap] = W2[unit(kap)][m]; kappa==38 (sat slot) -> bias row b2[m].
__device__ __forceinline__ half8v afrag2(const float* __restrict__ W2, const float* __restrict__ b2,
                                         int N2, int chunk, int q, int m) {
    float e[8];
#pragma unroll
    for (int j = 0; j < 8; j++) {
        int kap = 32 * chunk + 8 * q + j;
        bool dead, sat;
        int u = unitmap(kap, dead, sat);
        float f = 0.0f;
        if (m < N2) {
            if (sat)       f = b2[m];
            else if (!dead) f = W2[u * N2 + m];
        }
        e[j] = f;
    }
    uint4v d;
#pragma unroll
    for (int p = 0; p < 4; p++) d[p] = pkhf(e[2 * p], e[2 * p + 1]);
    return __builtin_bit_cast(half8v, d);
}

__global__ void __attribute__((amdgpu_flat_work_group_size(BLK, BLK), amdgpu_waves_per_eu(4, 4)))
node_kernel(const float* __restrict__ x0, const float* __restrict__ tt,
            const float* __restrict__ We1, const float* __restrict__ be1,
            const float* __restrict__ We2, const float* __restrict__ be2,
            const float* __restrict__ Wo1, const float* __restrict__ bo1,
            const float* __restrict__ Wo2, const float* __restrict__ bo2,
            const float* __restrict__ Wd1, const float* __restrict__ bd1,
            const float* __restrict__ Wd2, const float* __restrict__ bd2,
            float* __restrict__ out, int B, int T) {
    __shared__ float sdt[128];   // dt table (lgkm-side; loop stays vmcnt-free)
    {
        int idx = threadIdx.x;
        if (idx < T - 1) sdt[idx] = tt[idx + 1] - tt[idx];
    }
    __syncthreads();   // one-time; waves independent afterwards

    const int lane = threadIdx.x & 63;
    const int q    = lane >> 4;          // quad
    const int c    = lane & 15;          // batch col in B/CD frags; row m in A frags
    const int wid  = threadIdx.x >> 6;
    const int wbase = blockIdx.x * (NW * MPW) + wid * MPW;

    const f32x4 zero4 = {0.0f, 0.0f, 0.0f, 0.0f};
    // f16(1.0)=0x3C00 low half for q==0 lanes: z-frag bias slot (k=4) and the
    // chunk-1 sat slot (kappa 38).
    const unsigned biasdw = (q == 0) ? 0x3C00u : 0u;

    // Pade [5/4] tanh coefficients: tanh(x) ~ x(1 + x^2/9 + x^4/945) /
    //                                         (1 + 4x^2/9 + x^4/63)
    // Evaluated in packed f32 (v_pk_fma_f32); ONE v_rcp_f32 per value (the
    // f16-exp path needed exp+rcp = 2 quarter-rate trans per value -- R19
    // counter arithmetic: trans issue was ~75-85% of the VALU budget).
    const f32x2 pc1 = {0.111111111f, 0.111111111f};    // 1/9
    const f32x2 pc2 = {1.0582011e-3f, 1.0582011e-3f};  // 1/945
    const f32x2 pd1 = {0.444444444f, 0.444444444f};    // 4/9
    const f32x2 pd2 = {0.015873017f, 0.015873017f};    // 1/63
    const f32x2 onef2 = {1.0f, 1.0f};

    // tanh of a pair -> packed f16 dword.  Output clamped to [-1,1] via
    // v_med3_f32 (single full-rate instr): for |x|>~4 the rational exceeds
    // tanh only from above (1.0027 at x=8) so the clamp IS the saturation;
    // mid-range (|x|<2, where the ODE lives with Wo1~0.05) error ~1e-5,
    // better than the old f16-exp path (~1e-3).
    auto tanh2 = [&](float a, float b) -> unsigned {
        f32x2 x = {a, b};
        f32x2 s = x * x;                 // v_pk_mul_f32
        f32x2 n = s * pc2 + pc1;         // v_pk_fma_f32
        n = n * s + onef2;               // v_pk_fma_f32
        n = n * x;                       // v_pk_mul_f32 (numerator)
        f32x2 dd = s * pd2 + pd1;        // v_pk_fma_f32
        dd = dd * s + onef2;             // v_pk_fma_f32 (denominator)
        f32x2 r = {__builtin_amdgcn_rcpf(dd[0]),
                   __builtin_amdgcn_rcpf(dd[1])};   // 2x v_rcp_f32 (only trans)
        float t0 = __builtin_amdgcn_fmed3f(n[0] * r[0], -1.0f, 1.0f);  // v_med3
        float t1 = __builtin_amdgcn_fmed3f(n[1] * r[1], -1.0f, 1.0f);
        return pkhf(t0, t1);
    };

    // ---- persistent weight A-frags (f16; whole kernel) ----
    half8v A1o[4], A1d[4], A2o[2], A2d[2];
#pragma unroll
    for (int ti = 0; ti < 4; ti++) {
        A1o[ti] = afrag1(Wo1, bo1, LAT, ti, q, c, 1.0f);   // raw x for Pade
        A1d[ti] = afrag1(Wd1, bd1, LAT, ti, q, c, 1.0f);
    }
#pragma unroll
    for (int ch = 0; ch < 2; ch++) {
        A2o[ch] = afrag2(Wo2, bo2, LAT, ch, q, c);
        A2d[ch] = afrag2(Wd2, bd2, 1, ch, q, c);
    }

    // ---- Encoder (transient f16 frags), relu in f32 then pack ----
    f32x4 z;
    {
        uint4v bx = {0u, 0u, 0u, 0u};
        if (q == 0) {  // x at k=0,1; bias 1.0 at k=4
            bx[0] = pkhf(x0[2 * (wbase + c)], x0[2 * (wbase + c) + 1]);
            bx[2] = 0x3C00u;
        }
        half8v Bx = __builtin_bit_cast(half8v, bx);
        f32x4 h0 = MFMAH(afrag1(We1, be1, 2, 0, q, c, 1.0f), Bx, zero4);
        f32x4 h1 = MFMAH(afrag1(We1, be1, 2, 1, q, c, 1.0f), Bx, zero4);
        f32x4 h2 = MFMAH(afrag1(We1, be1, 2, 2, q, c, 1.0f), Bx, zero4);
        f32x4 h3 = MFMAH(afrag1(We1, be1, 2, 3, q, c, 1.0f), Bx, zero4);
        uint4v d0 = {pkhf(fmaxf(h0[0], 0.f), fmaxf(h0[1], 0.f)), pkhf(fmaxf(h0[2], 0.f), fmaxf(h0[3], 0.f)),
                     pkhf(fmaxf(h1[0], 0.f), fmaxf(h1[1], 0.f)), pkhf(fmaxf(h1[2], 0.f), fmaxf(h1[3], 0.f))};
        uint4v d1 = {pkhf(fmaxf(h2[0], 0.f), fmaxf(h2[1], 0.f)), pkhf(fmaxf(h2[2], 0.f), fmaxf(h2[3], 0.f)),
                     pkhf(fmaxf(h3[0], 0.f), fmaxf(h3[1], 0.f)), biasdw};
        z = MFMAH(afrag2(We2, be2, 16, 1, q, c), __builtin_bit_cast(half8v, d1),
            MFMAH(afrag2(We2, be2, 16, 0, q, c), __builtin_bit_cast(half8v, d0), zero4));
    }

    // z (CD layout: lat 4q+r, batch c) -> GEMM1 B-frag: k(j<4)=lat 4q+j, bias at k=4
    auto mkzfrag = [&](f32x4 zz) -> half8v {
        uint4v d = {pkhf(zz[0], zz[1]), pkhf(zz[2], zz[3]), biasdw, 0u};
        return __builtin_bit_cast(half8v, d);
    };

    // ODE func: 6 MFMA + packed-f32 Pade tanh on 7 value-pairs (14 values).
    // Trans ops per call: 14 (was 28 exp+rcp); everything else full-rate.
    auto odef = [&](half8v zf) -> f32x4 {
        f32x4 h0 = MFMAH(A1o[0], zf, zero4);
        f32x4 h1 = MFMAH(A1o[1], zf, zero4);
        f32x4 h2 = MFMAH(A1o[2], zf, zero4);
        f32x4 h3 = MFMAH(A1o[3], zf, zero4);
        uint4v d0 = {tanh2(h0[0], h0[1]), tanh2(h0[2], h0[3]),
                     tanh2(h1[0], h1[1]), tanh2(h1[2], h1[3])};
        uint4v d1 = {tanh2(h2[0], h2[1]), tanh2(h2[2], h2[3]),
                     tanh2(h3[0], h3[1]), biasdw};
        return MFMAH(A2o[1], __builtin_bit_cast(half8v, d1),
               MFMAH(A2o[0], __builtin_bit_cast(half8v, d0), zero4));
    };

    // decoder: relu in f32 (full-rate), pack pairs; y[c] in reg0 of q==0 lanes
    auto decode = [&](half8v zf) -> f32x4 {
        f32x4 h0 = MFMAH(A1d[0], zf, zero4);
        f32x4 h1 = MFMAH(A1d[1], zf, zero4);
        f32x4 h2 = MFMAH(A1d[2], zf, zero4);
        f32x4 h3 = MFMAH(A1d[3], zf, zero4);
        uint4v d0 = {pkhf(fmaxf(h0[0], 0.f), fmaxf(h0[1], 0.f)), pkhf(fmaxf(h0[2], 0.f), fmaxf(h0[3], 0.f)),
                     pkhf(fmaxf(h1[0], 0.f), fmaxf(h1[1], 0.f)), pkhf(fmaxf(h1[2], 0.f), fmaxf(h1[3], 0.f))};
        uint4v d1 = {pkhf(fmaxf(h2[0], 0.f), fmaxf(h2[1], 0.f)), pkhf(fmaxf(h2[2], 0.f), fmaxf(h2[3], 0.f)),
                     pkhf(fmaxf(h3[0], 0.f), fmaxf(h3[1], 0.f)), biasdw};
        return MFMAH(A2d[1], __builtin_bit_cast(half8v, d1),
               MFMAH(A2d[0], __builtin_bit_cast(half8v, d0), zero4));
    };

    // ---- main time loop: register dataflow; only VMEM op is the out store ----
    for (int s = 0;; s++) {
        float dt = sdt[s];
        half8v zf = mkzfrag(z);
        f32x4 y = decode(zf);
        if (lane < 16) out[(size_t)s * B + wbase + c] = y[0];

        if (s == T - 1) break;

        f32x4 k = odef(zf);                          // k1 (shares zf with decode)
        f32x4 ksum = k;
        f32x4 ztmp = z + (0.5f * dt) * k;
        k = odef(mkzfrag(ztmp));                     // k2
        ksum += 2.0f * k;
        ztmp = z + (0.5f * dt) * k;
        k = odef(mkzfrag(ztmp));                     // k3
        ksum += 2.0f * k;
        ztmp = z + dt * k;
        k = odef(mkzfrag(ztmp));                     // k4
        z = z + (dt * (1.0f / 6.0f)) * (ksum + k);
    }
}

extern "C" void kernel_launch(void* const* d_in, const int* in_sizes, int n_in,
                              void* d_out, int out_size, void* d_ws, size_t ws_size,
                              hipStream_t stream) {
    const float* x0  = (const float*)d_in[0];
    const float* t   = (const float*)d_in[1];
    const float* We1 = (const float*)d_in[2];
    const float* be1 = (const float*)d_in[3];
    const float* We2 = (const float*)d_in[4];
    const float* be2 = (const float*)d_in[5];
    const float* Wo1 = (const float*)d_in[6];
    const float* bo1 = (const float*)d_in[7];
    const float* Wo2 = (const float*)d_in[8];
    const float* bo2 = (const float*)d_in[9];
    const float* Wd1 = (const float*)d_in[10];
    const float* bd1 = (const float*)d_in[11];
    const float* Wd2 = (const float*)d_in[12];
    const float* bd2 = (const float*)d_in[13];
    float* out = (float*)d_out;

    int B = in_sizes[0] / 2;   // 65536
    int T = in_sizes[1];       // 100

    dim3 block(BLK);
    dim3 grid(B / (NW * MPW)); // 1024 blocks, 4 waves each
    hipLaunchKernelGGL(node_kernel, grid, block, 0, stream,
                       x0, t, We1, be1, We2, be2, Wo1, bo1, Wo2, bo2,
                       Wd1, bd1, Wd2, bd2, out, B, T);
}

// Round 3
// 423.190 us; speedup vs baseline: 1.2346x; 1.2346x over previous
//
#include <hip/hip_runtime.h>
#include <hip/hip_fp16.h>

#define HID 50
#define LAT 16
#define NW  4          // waves per block (independent after one-time dt staging)
#define BLK (NW * 64)
#define MPW 16         // batch elements per wave (one MFMA M-tile)

typedef __attribute__((ext_vector_type(8))) _Float16 half8v;  // 8 f16 = 4 VGPRs
typedef __attribute__((ext_vector_type(4))) float f32x4;
typedef __attribute__((ext_vector_type(2))) float f32x2;      // v_pk_*_f32 pair
typedef __attribute__((ext_vector_type(4))) unsigned uint4v;

#define MFMAH(a, b, c) __builtin_amdgcn_mfma_f32_16x16x32_f16(a, b, c, 0, 0, 0)

// pack two fp32 -> dword of 2 f16 (v_cvt_pkrtz_f16_f32, 1 instr)
__device__ __forceinline__ unsigned pkhf(float lo, float hi) {
    __half2 h = __float22half2_rn(float2{lo, hi});
    unsigned r;
    __builtin_memcpy(&r, &h, 4);
    return r;
}

// kappa-label -> hidden-unit map (R15 repack).  Tiles 0-2 hold real units
// 0..47; tile 3 holds units 48,49 at m=0,1 (q=0), the bias/sat slot at
// kappa==38 (m=2, q=0), everything else dead.  odef/decode evaluate the
// activation on 14 lane-values; the sat slot is the constant biasdw dword.
__device__ __forceinline__ int unitmap(int k, bool& dead, bool& sat) {
    dead = false; sat = false;
    int u = k;
    if (k == 36)                          u = 48;
    else if (k == 37)                     u = 49;
    else if (k == 38)                     sat = true;
    else if (k == 39)                     dead = true;
    else if (k >= 44 && k < 48)           dead = true;
    else if ((k >= 48 && k < 52) || (k >= 56 && k < 60)) u = k - 12;
    else if (k >= 52 && k < 56)           dead = true;
    else if (k >= 60)                     dead = true;
    return u;   // k<36 (not 36-39) and 40-43: identity
}

// ---- A-frag builders (weights as f16 MFMA A-operand; one-time setup) ----
// Layer-1: A-row m of tile ti holds unit unitmap(kappa(ti,m)),
// kappa(ti,m)=32*(ti>>1)+8*(m>>2)+4*(ti&1)+(m&3) -- CD regs land exactly on
// GEMM2 B-frag slots.  k-slot (q,j): j<4 -> input row 4q+j; (q==0,j==4) ->
// bias*scale.  sat/dead columns all-zero (bias enters via GEMM2 B const).
__device__ __forceinline__ half8v afrag1(const float* __restrict__ W, const float* __restrict__ bias,
                                         int Kreal, int ti, int q, int m, float scale) {
    int kap = 32 * (ti >> 1) + 8 * (m >> 2) + 4 * (ti & 1) + (m & 3);
    bool dead, sat;
    int u = unitmap(kap, dead, sat);
    float e[8];
#pragma unroll
    for (int j = 0; j < 8; j++) {
        float f = 0.0f;
        if (!dead && !sat) {
            if (j < 4) {
                int row = 4 * q + j;
                if (row < Kreal) f = W[row * HID + u] * scale;
            } else if (j == 4 && q == 0) f = bias[u] * scale;
        }
        e[j] = f;
    }
    uint4v d;
#pragma unroll
    for (int p = 0; p < 4; p++) d[p] = pkhf(e[2 * p], e[2 * p + 1]);
    return __builtin_bit_cast(half8v, d);
}

// Layer-2: A2[m][kap] = W2[unit(kap)][m]; kappa==38 (sat slot) -> bias row b2[m].
__device__ __forceinline__ half8v afrag2(const float* __restrict__ W2, const float* __restrict__ b2,
                                         int N2, int chunk, int q, int m) {
    float e[8];
#pragma unroll
    for (int j = 0; j < 8; j++) {
        int kap = 32 * chunk + 8 * q + j;
        bool dead, sat;
        int u = unitmap(kap, dead, sat);
        float f = 0.0f;
        if (m < N2) {
            if (sat)       f = b2[m];
            else if (!dead) f = W2[u * N2 + m];
        }
        e[j] = f;
    }
    uint4v d;
#pragma unroll
    for (int p = 0; p < 4; p++) d[p] = pkhf(e[2 * p], e[2 * p + 1]);
    return __builtin_bit_cast(half8v, d);
}

__global__ void __attribute__((amdgpu_flat_work_group_size(BLK, BLK), amdgpu_waves_per_eu(4, 4)))
node_kernel(const float* __restrict__ x0, const float* __restrict__ tt,
            const float* __restrict__ We1, const float* __restrict__ be1,
            const float* __restrict__ We2, const float* __restrict__ be2,
            const float* __restrict__ Wo1, const float* __restrict__ bo1,
            const float* __restrict__ Wo2, const float* __restrict__ bo2,
            const float* __restrict__ Wd1, const float* __restrict__ bd1,
            const float* __restrict__ Wd2, const float* __restrict__ bd2,
            float* __restrict__ out, int B, int T) {
    __shared__ float sdt[128];   // dt table (lgkm-side; loop stays vmcnt-free)
    {
        int idx = threadIdx.x;
        if (idx < T - 1) sdt[idx] = tt[idx + 1] - tt[idx];
    }
    __syncthreads();   // one-time; waves independent afterwards

    const int lane = threadIdx.x & 63;
    const int q    = lane >> 4;          // quad
    const int c    = lane & 15;          // batch col in B/CD frags; row m in A frags
    const int wid  = threadIdx.x >> 6;
    const int wbase = blockIdx.x * (NW * MPW) + wid * MPW;

    const f32x4 zero4 = {0.0f, 0.0f, 0.0f, 0.0f};
    // f16(1.0)=0x3C00 low half for q==0 lanes: z-frag bias slot (k=4) and the
    // chunk-1 sat slot (kappa 38).
    const unsigned biasdw = (q == 0) ? 0x3C00u : 0u;

    // TRANS-FREE tanh.  R19 R0/R2 counter calibration: every transcendental
    // (v_exp_f16, v_rcp_f16, v_rcp_f32) occupies the SIMD ~15-25 cyc for a
    // wave64 (1/8-rate trans unit); trans issue was ~75-80% of R0's VALU
    // budget, and the R2 Pade (14 rcp + 2x full-rate count) regressed.
    // So: odd polynomial tanh(x) ~ x*P(x^2), P quartic (degree-9 odd), fit
    // at Chebyshev nodes on |x|<=2, input clamped to [-2,2] by v_med3_f32.
    // Max |err| ~9e-4 on [-2,2] -- same order as the f16-exp path.  ODE
    // pre-activations are |x|~<1 (Wo1 ~0.05 x 16 latents), clamp is margin.
    // Cost/pair: 2 med3 + 6 pk-f32 + 1 cvt_pk = 9 instrs, ZERO trans.
    const f32x2 tc0 = { 0.998805f,  0.998805f};
    const f32x2 tc1 = {-0.317916f, -0.317916f};
    const f32x2 tc2 = { 0.097206f,  0.097206f};
    const f32x2 tc3 = {-0.018404f, -0.018404f};
    const f32x2 tc4 = { 0.001476f,  0.001476f};

    auto tanh2 = [&](float a, float b) -> unsigned {
        f32x2 x;
        x[0] = __builtin_amdgcn_fmed3f(a, -2.0f, 2.0f);   // clamp = saturation
        x[1] = __builtin_amdgcn_fmed3f(b, -2.0f, 2.0f);
        f32x2 s = x * x;                 // v_pk_mul_f32
        f32x2 p = s * tc4 + tc3;         // v_pk_fma_f32 (Horner)
        p = p * s + tc2;
        p = p * s + tc1;
        p = p * s + tc0;
        p = p * x;                       // v_pk_mul_f32
        return pkhf(p[0], p[1]);
    };

    // ---- persistent weight A-frags (f16; whole kernel) ----
    half8v A1o[4], A1d[4], A2o[2], A2d[2];
#pragma unroll
    for (int ti = 0; ti < 4; ti++) {
        A1o[ti] = afrag1(Wo1, bo1, LAT, ti, q, c, 1.0f);   // raw x for poly
        A1d[ti] = afrag1(Wd1, bd1, LAT, ti, q, c, 1.0f);
    }
#pragma unroll
    for (int ch = 0; ch < 2; ch++) {
        A2o[ch] = afrag2(Wo2, bo2, LAT, ch, q, c);
        A2d[ch] = afrag2(Wd2, bd2, 1, ch, q, c);
    }

    // ---- Encoder (transient f16 frags), relu in f32 then pack ----
    f32x4 z;
    {
        uint4v bx = {0u, 0u, 0u, 0u};
        if (q == 0) {  // x at k=0,1; bias 1.0 at k=4
            bx[0] = pkhf(x0[2 * (wbase + c)], x0[2 * (wbase + c) + 1]);
            bx[2] = 0x3C00u;
        }
        half8v Bx = __builtin_bit_cast(half8v, bx);
        f32x4 h0 = MFMAH(afrag1(We1, be1, 2, 0, q, c, 1.0f), Bx, zero4);
        f32x4 h1 = MFMAH(afrag1(We1, be1, 2, 1, q, c, 1.0f), Bx, zero4);
        f32x4 h2 = MFMAH(afrag1(We1, be1, 2, 2, q, c, 1.0f), Bx, zero4);
        f32x4 h3 = MFMAH(afrag1(We1, be1, 2, 3, q, c, 1.0f), Bx, zero4);
        uint4v d0 = {pkhf(fmaxf(h0[0], 0.f), fmaxf(h0[1], 0.f)), pkhf(fmaxf(h0[2], 0.f), fmaxf(h0[3], 0.f)),
                     pkhf(fmaxf(h1[0], 0.f), fmaxf(h1[1], 0.f)), pkhf(fmaxf(h1[2], 0.f), fmaxf(h1[3], 0.f))};
        uint4v d1 = {pkhf(fmaxf(h2[0], 0.f), fmaxf(h2[1], 0.f)), pkhf(fmaxf(h2[2], 0.f), fmaxf(h2[3], 0.f)),
                     pkhf(fmaxf(h3[0], 0.f), fmaxf(h3[1], 0.f)), biasdw};
        z = MFMAH(afrag2(We2, be2, 16, 1, q, c), __builtin_bit_cast(half8v, d1),
            MFMAH(afrag2(We2, be2, 16, 0, q, c), __builtin_bit_cast(half8v, d0), zero4));
    }

    // z (CD layout: lat 4q+r, batch c) -> GEMM1 B-frag: k(j<4)=lat 4q+j, bias at k=4
    auto mkzfrag = [&](f32x4 zz) -> half8v {
        uint4v d = {pkhf(zz[0], zz[1]), pkhf(zz[2], zz[3]), biasdw, 0u};
        return __builtin_bit_cast(half8v, d);
    };

    // ODE func: 6 MFMA + trans-free poly tanh on 7 value-pairs (14 values).
    auto odef = [&](half8v zf) -> f32x4 {
        f32x4 h0 = MFMAH(A1o[0], zf, zero4);
        f32x4 h1 = MFMAH(A1o[1], zf, zero4);
        f32x4 h2 = MFMAH(A1o[2], zf, zero4);
        f32x4 h3 = MFMAH(A1o[3], zf, zero4);
        uint4v d0 = {tanh2(h0[0], h0[1]), tanh2(h0[2], h0[3]),
                     tanh2(h1[0], h1[1]), tanh2(h1[2], h1[3])};
        uint4v d1 = {tanh2(h2[0], h2[1]), tanh2(h2[2], h2[3]),
                     tanh2(h3[0], h3[1]), biasdw};
        return MFMAH(A2o[1], __builtin_bit_cast(half8v, d1),
               MFMAH(A2o[0], __builtin_bit_cast(half8v, d0), zero4));
    };

    // decoder: relu in f32 (full-rate), pack pairs; y[c] in reg0 of q==0 lanes
    auto decode = [&](half8v zf) -> f32x4 {
        f32x4 h0 = MFMAH(A1d[0], zf, zero4);
        f32x4 h1 = MFMAH(A1d[1], zf, zero4);
        f32x4 h2 = MFMAH(A1d[2], zf, zero4);
        f32x4 h3 = MFMAH(A1d[3], zf, zero4);
        uint4v d0 = {pkhf(fmaxf(h0[0], 0.f), fmaxf(h0[1], 0.f)), pkhf(fmaxf(h0[2], 0.f), fmaxf(h0[3], 0.f)),
                     pkhf(fmaxf(h1[0], 0.f), fmaxf(h1[1], 0.f)), pkhf(fmaxf(h1[2], 0.f), fmaxf(h1[3], 0.f))};
        uint4v d1 = {pkhf(fmaxf(h2[0], 0.f), fmaxf(h2[1], 0.f)), pkhf(fmaxf(h2[2], 0.f), fmaxf(h2[3], 0.f)),
                     pkhf(fmaxf(h3[0], 0.f), fmaxf(h3[1], 0.f)), biasdw};
        return MFMAH(A2d[1], __builtin_bit_cast(half8v, d1),
               MFMAH(A2d[0], __builtin_bit_cast(half8v, d0), zero4));
    };

    // ---- main time loop: register dataflow; only VMEM op is the out store ----
    for (int s = 0;; s++) {
        float dt = sdt[s];
        half8v zf = mkzfrag(z);
        f32x4 y = decode(zf);
        if (lane < 16) out[(size_t)s * B + wbase + c] = y[0];

        if (s == T - 1) break;

        f32x4 k = odef(zf);                          // k1 (shares zf with decode)
        f32x4 ksum = k;
        f32x4 ztmp = z + (0.5f * dt) * k;
        k = odef(mkzfrag(ztmp));                     // k2
        ksum += 2.0f * k;
        ztmp = z + (0.5f * dt) * k;
        k = odef(mkzfrag(ztmp));                     // k3
        ksum += 2.0f * k;
        ztmp = z + dt * k;
        k = odef(mkzfrag(ztmp));                     // k4
        z = z + (dt * (1.0f / 6.0f)) * (ksum + k);
    }
}

extern "C" void kernel_launch(void* const* d_in, const int* in_sizes, int n_in,
                              void* d_out, int out_size, void* d_ws, size_t ws_size,
                              hipStream_t stream) {
    const float* x0  = (const float*)d_in[0];
    const float* t   = (const float*)d_in[1];
    const float* We1 = (const float*)d_in[2];
    const float* be1 = (const float*)d_in[3];
    const float* We2 = (const float*)d_in[4];
    const float* be2 = (const float*)d_in[5];
    const float* Wo1 = (const float*)d_in[6];
    const float* bo1 = (const float*)d_in[7];
    const float* Wo2 = (const float*)d_in[8];
    const float* bo2 = (const float*)d_in[9];
    const float* Wd1 = (const float*)d_in[10];
    const float* bd1 = (const float*)d_in[11];
    const float* Wd2 = (const float*)d_in[12];
    const float* bd2 = (const float*)d_in[13];
    float* out = (float*)d_out;

    int B = in_sizes[0] / 2;   // 65536
    int T = in_sizes[1];       // 100

    dim3 block(BLK);
    dim3 grid(B / (NW * MPW)); // 1024 blocks, 4 waves each
    hipLaunchKernelGGL(node_kernel, grid, block, 0, stream,
                       x0, t, We1, be1, We2, be2, Wo1, bo1, Wo2, bo2,
                       Wd1, bd1, Wd2, bd2, out, B, T);
}